// Round 12
// baseline (153.501 us; speedup 1.0000x reference)
//
#include <hip/hip_runtime.h>
#include <math.h>
#include <stdint.h>

// Problem constants
#define NIMG 512          // B*C = 64*8
#define HH   256          // H
#define MM   32           // M (kept modes per axis)
#define EPSF 1e-8f
#define PADQ 9            // T2q row stride in float2 (72B rows, conflict-free)

// d_out float offsets (outputs concatenated flat in reference return order)
#define O0 0u             // modal_energies        [512][32][32]
#define O1 524288u        // modal_uncertainties   [512][32][32]
#define O2 1048576u       // energy_fractions      [512][32][32]
#define O3 1572864u       // weighted_importance   [512][32][32]
#define O4 2097152u       // uncertainty_spectrum  [32][32]
#define O5 2098176u       // energy_spectrum       [32][32]
#define O6 2099200u       // modal_errors          [512][32][32]
#define O7 2623488u       // calibration_scores    [32][32]

// d_ws float offsets
#define PM_OFF  512                          // pred modes [512][32][32][2]
#define GM_OFF  (512 + NIMG*MM*MM*2)         // gt modes
#define TOT_OFF (512 + 2*NIMG*MM*MM*2)       // per-image total energy [512]

// async global->LDS: 64 lanes x 16B; LDS dest = wave-uniform base + lane*16,
// global src per-lane. size must be the literal 16.
#define GLOAD_LDS(gsrc, ldst)                                             \
  __builtin_amdgcn_global_load_lds(                                       \
      (const __attribute__((address_space(1))) unsigned int*)(gsrc),      \
      (__attribute__((address_space(3))) unsigned int*)(ldst), 16, 0, 0)

// ---------------------------------------------------------------------------
// Truncated 2D DFT: one block per (image, tensor). 256 threads (thread = n2).
// Occupancy design: LDS = 45KB -> 3 blocks/CU (12 waves/CU, 3/SIMD);
//   waves_per_eu(3,3) pins the 170-VGPR budget so the 64 accumulator floats
//   live in arch VGPRs.
// DMA schedule (r11 lesson): compiler emits vmcnt(0) before every s_barrier,
//   so DMA must be issued IMMEDIATELY AFTER a barrier and waited at the NEXT
//   one -> one full body (~1200 wall cycles at 3 waves/SIMD) of latency
//   cover. 3-slot ring: read slot a%3, issue slot (a+2)%3.
// Stage 1 (DIT-8 over n1 = a + 32b): per a, constant-twiddle 8-pt real DFT
//   over b, then X[8m+r] += W32^{am} * (W256^{ar} * Z[r]); twiddles from a
//   2KB LDS table (wave-uniform broadcast reads).
// Stage 2: FOUR k1-quarter passes through T2q[256][PADQ] (18.4KB). Thread ->
//   (k1q = l>>3, k2 = 4*(l&7)+wave); radix-4 fold over n2, residue k2%4
//   wave-uniform/branchless; per-mode rotator by complex recurrence.
__global__ __attribute__((amdgpu_waves_per_eu(3, 3))) __launch_bounds__(256)
void dft_kernel(
    const float* __restrict__ pred, const float* __restrict__ gt,
    float* __restrict__ Pm, float* __restrict__ Gm,
    float* __restrict__ tot, float* __restrict__ out_energy)
{
  __shared__ __align__(16) float2 T2q[256 * PADQ];  // 18432 B
  __shared__ float2 tws[256];                       // 2 KB twiddle table
  __shared__ float  xbuf[3][8][256];                // 24 KB input ring
  __shared__ float  red[4];

  const int t    = threadIdx.x;
  const int w    = t >> 6;           // wave 0..3
  const int l    = t & 63;
  const int img  = blockIdx.x & (NIMG - 1);
  const int isGt = blockIdx.x >> 9;
  const float* __restrict__ x =
      (isGt ? gt : pred) + (size_t)img * (HH * HH);
  float* __restrict__ xbf = &xbuf[0][0][0];

  // build twiddle table: tws[i] = (cos, sin)(2*pi*i/256)
  {
    float sn, cs;
    __sincosf((float)(2.0 * M_PI / 256.0) * (float)t, &sn, &cs);
    tws[t] = make_float2(cs, sn);
  }

  // wave w DMAs rows b = 2w, 2w+1 of iteration aa into ring slot aa%3
#define ISSUE(aa)                                                         \
  {                                                                       \
    int sl_ = (aa) % 3;                                                   \
    const float* g0 = x + ((aa) + 32 * (2 * w))     * 256 + 4 * l;        \
    const float* g1 = x + ((aa) + 32 * (2 * w + 1)) * 256 + 4 * l;        \
    float* d0 = xbf + ((sl_ * 8 + 2 * w)     << 8);                       \
    float* d1 = xbf + ((sl_ * 8 + 2 * w + 1) << 8);                       \
    GLOAD_LDS(g0, d0);                                                    \
    GLOAD_LDS(g1, d1);                                                    \
  }

#define LOADL(V, aa)                                                      \
  {                                                                       \
    int bo = (((aa) % 3) * 8) * 256 + t;                                  \
    V[0] = xbf[bo];        V[1] = xbf[bo + 256];                          \
    V[2] = xbf[bo + 512];  V[3] = xbf[bo + 768];                          \
    V[4] = xbf[bo + 1024]; V[5] = xbf[bo + 1280];                         \
    V[6] = xbf[bo + 1536]; V[7] = xbf[bo + 1792];                         \
  }

  // ---- stage 1: DIT-8 over n1 ----
  float accR[32], accI[32];
#pragma unroll
  for (int k = 0; k < 32; ++k) { accR[k] = 0.f; accI[k] = 0.f; }

#define ACC4(r, Yr, Yi)                                                   \
    accR[(r)]    += (Yr);  accI[(r)]    += (Yi);                          \
    accR[8+(r)]  = fmaf(m1r,(Yr), fmaf( m1s,(Yi), accR[8+(r)]));          \
    accI[8+(r)]  = fmaf(m1r,(Yi), fmaf(-m1s,(Yr), accI[8+(r)]));          \
    accR[16+(r)] = fmaf(m2r,(Yr), fmaf( m2s,(Yi), accR[16+(r)]));         \
    accI[16+(r)] = fmaf(m2r,(Yi), fmaf(-m2s,(Yr), accI[16+(r)]));         \
    accR[24+(r)] = fmaf(m3r,(Yr), fmaf( m3s,(Yi), accR[24+(r)]));         \
    accI[24+(r)] = fmaf(m3r,(Yi), fmaf(-m3s,(Yr), accI[24+(r)]));

#define CPLX_R(r, aa, Zr, Zi)                                             \
    {                                                                     \
      float2 tt = tws[((r) * (aa)) & 255];                                \
      float Yr = fmaf(tt.x, (Zr),  tt.y * (Zi));                          \
      float Yi = fmaf(tt.x, (Zi), -(tt.y * (Zr)));                        \
      ACC4(r, Yr, Yi)                                                     \
    }

#define BODY(V, aa)                                                       \
  {                                                                       \
    float v0=V[0],v1=V[1],v2=V[2],v3=V[3],v4=V[4],v5=V[5],v6=V[6],v7=V[7];\
    float w0=v0+v4, w1=v1+v5, w2=v2+v6, w3=v3+v7;                         \
    float d0=v0-v4, d1=v1-v5, d2=v2-v6, d3=v3-v7;                         \
    float A0=w0+w2, A1=w0-w2, A2=w1+w3, A3=w1-w3;                         \
    float Z0=A0+A2, Z4=A0-A2;                                             \
    float Z2r=A1, Z2i=-A3;                                                \
    const float SQ = 0.70710678f;                                         \
    float pp=SQ*(d1-d3), qq2=SQ*(d1+d3);                                  \
    float Z1r=d0+pp, Z1i=-(d2+qq2);                                       \
    float Z3r=d0-pp, Z3i=d2-qq2;                                          \
    float2 tm1 = tws[( 8*(aa)) & 255];                                    \
    float2 tm2 = tws[(16*(aa)) & 255];                                    \
    float2 tm3 = tws[(24*(aa)) & 255];                                    \
    float m1r = tm1.x, m1s = tm1.y;                                       \
    float m2r = tm2.x, m2s = tm2.y;                                       \
    float m3r = tm3.x, m3s = tm3.y;                                       \
    /* r=0: Y = (Z0, 0) */                                                \
    accR[0] += Z0;                                                        \
    accR[8]  = fmaf(m1r,Z0,accR[8]);  accI[8]  = fmaf(-m1s,Z0,accI[8]);   \
    accR[16] = fmaf(m2r,Z0,accR[16]); accI[16] = fmaf(-m2s,Z0,accI[16]);  \
    accR[24] = fmaf(m3r,Z0,accR[24]); accI[24] = fmaf(-m3s,Z0,accI[24]);  \
    /* r=4: Y = W256^{4a} * Z4 (Z4 real) */                               \
    { float2 tt = tws[(4*(aa)) & 255];                                    \
      float Yr = tt.x * Z4, Yi = -(tt.y * Z4);                            \
      ACC4(4, Yr, Yi) }                                                   \
    CPLX_R(1, (aa), Z1r,  Z1i)                                            \
    CPLX_R(2, (aa), Z2r,  Z2i)                                            \
    CPLX_R(3, (aa), Z3r,  Z3i)                                            \
    CPLX_R(5, (aa), Z3r, -Z3i)                                            \
    CPLX_R(6, (aa), Z2r, -Z2i)                                            \
    CPLX_R(7, (aa), Z1r, -Z1i)                                            \
  }

  // prefill slots 0 and 1
  ISSUE(0)
  ISSUE(1)

#pragma unroll 1
  for (int a = 0; a < 32; ++a) {
    __syncthreads();     // slot a%3 landed (vmcnt(0) drain); slot (a+2)%3 free
    if (a < 30) { ISSUE(a + 2) }   // issued right after barrier -> waited at
    float V[8];                    // NEXT barrier, one full body later
    LOADL(V, a)
    BODY(V, a)
  }
#undef BODY
#undef LOADL
#undef ISSUE
#undef CPLX_R
#undef ACC4

  // ---- stage 2: four k1-quarter passes, radix-4 fold over n2 ----
  float* __restrict__ Mo = (isGt ? Gm : Pm) + (size_t)img * (MM * MM * 2);
  const int wv  = w;             // residue k2 % 4 (wave-uniform)
  const int k1q = l >> 3;        // 0..7
  const int k2  = 4 * (l & 7) + wv;
  float sR, cR;
  __sincosf((float)(-2.0 * M_PI / 256.0) * (float)k2, &sR, &cR);
  const float se = (wv & 1) ? -1.f : 1.f;     // fold sign for T_c/T_3
  const float cc = (wv < 2) ? 1.f : -1.f;     // second-term sign
  const bool  ev = (wv & 1) == 0;
  float eacc = 0.f;

#define FLUSH(P)                                                          \
  {                                                                       \
    T2q[t * PADQ + 0] = make_float2(accR[8*(P)+0], accI[8*(P)+0]);        \
    T2q[t * PADQ + 1] = make_float2(accR[8*(P)+1], accI[8*(P)+1]);        \
    T2q[t * PADQ + 2] = make_float2(accR[8*(P)+2], accI[8*(P)+2]);        \
    T2q[t * PADQ + 3] = make_float2(accR[8*(P)+3], accI[8*(P)+3]);        \
    T2q[t * PADQ + 4] = make_float2(accR[8*(P)+4], accI[8*(P)+4]);        \
    T2q[t * PADQ + 5] = make_float2(accR[8*(P)+5], accI[8*(P)+5]);        \
    T2q[t * PADQ + 6] = make_float2(accR[8*(P)+6], accI[8*(P)+6]);        \
    T2q[t * PADQ + 7] = make_float2(accR[8*(P)+7], accI[8*(P)+7]);        \
  }

#define PASS(P)                                                           \
  {                                                                       \
    float wr = 1.f, wi = 0.f, Xr = 0.f, Xi = 0.f;                         \
    _Pragma("unroll 4")                                                   \
    for (int n2 = 0; n2 < 64; ++n2) {                                     \
      float2 T0 = T2q[(n2      ) * PADQ + k1q];                           \
      float2 T1 = T2q[(n2 +  64) * PADQ + k1q];                           \
      float2 Tc = T2q[(n2 + 128) * PADQ + k1q];                           \
      float2 T3 = T2q[(n2 + 192) * PADQ + k1q];                           \
      float sr = fmaf(se, Tc.x, T0.x), si = fmaf(se, Tc.y, T0.y);         \
      float tr = fmaf(se, T3.x, T1.x), ti = fmaf(se, T3.y, T1.y);         \
      float ur = ev ? tr : ti;                                            \
      float ui = ev ? ti : -tr;                                           \
      float yr = fmaf(cc, ur, sr), yi = fmaf(cc, ui, si);                 \
      Xr = fmaf(wr, yr, fmaf(-wi, yi, Xr));                               \
      Xi = fmaf(wr, yi, fmaf( wi, yr, Xi));                               \
      float nr_ = fmaf(wr, cR, -(wi * sR));                               \
      float ni_ = fmaf(wr, sR,  (wi * cR));                               \
      wr = nr_; wi = ni_;                                                 \
    }                                                                     \
    const int k1g  = 8 * (P) + k1q;                                       \
    const int midx = k1g * MM + k2;                                       \
    ((float2*)Mo)[midx] = make_float2(Xr, Xi);                            \
    if (!isGt) {                                                          \
      float en = fmaf(Xr, Xr, Xi * Xi);                                   \
      out_energy[(size_t)img * (MM * MM) + midx] = en;                    \
      eacc += en;                                                         \
    }                                                                     \
  }

  FLUSH(0)
  __syncthreads();
  PASS(0)
  __syncthreads();
  FLUSH(1)
  __syncthreads();
  PASS(1)
  __syncthreads();
  FLUSH(2)
  __syncthreads();
  PASS(2)
  __syncthreads();
  FLUSH(3)
  __syncthreads();
  PASS(3)
#undef FLUSH
#undef PASS

  if (!isGt) {   // block-uniform branch
#pragma unroll
    for (int off = 32; off >= 1; off >>= 1) eacc += __shfl_down(eacc, off);
    if ((t & 63) == 0) red[t >> 6] = eacc;
    __syncthreads();
    if (t == 0) tot[img] = (red[0] + red[1]) + (red[2] + red[3]);
  }
}

// ---------------------------------------------------------------------------
// Per-mode MLP + elementwise outputs. One thread per (img, mode).
__global__ __launch_bounds__(256) void mlp_kernel(
    const float* __restrict__ Pm, const float* __restrict__ Gm,
    const float* __restrict__ tot,
    const float* __restrict__ W1, const float* __restrict__ b1,
    const float* __restrict__ W2, const float* __restrict__ b2,
    const float* __restrict__ W3, const float* __restrict__ b3,
    float* __restrict__ out)
{
  int gid = blockIdx.x * 256 + threadIdx.x;   // 0 .. 524287
  int img = gid >> 10;

  float2 pm = *(const float2*)&Pm[2 * (size_t)gid];
  float2 gm = *(const float2*)&Gm[2 * (size_t)gid];

  float er = pm.x - gm.x, ei = pm.y - gm.y;
  float merr   = fmaf(er, er, ei * ei);
  float energy = fmaf(pm.x, pm.x, pm.y * pm.y);
  float frac   = energy / (tot[img] + EPSF);

  float h1[64];
#pragma unroll
  for (int j = 0; j < 64; ++j)
    h1[j] = fmaxf(fmaf(pm.x, W1[j], fmaf(pm.y, W1[64 + j], b1[j])), 0.f);

  float h2[32];
#pragma unroll
  for (int k = 0; k < 32; ++k) h2[k] = b2[k];
#pragma unroll
  for (int j = 0; j < 64; ++j) {
#pragma unroll
    for (int k = 0; k < 32; ++k)
      h2[k] = fmaf(h1[j], W2[j * 32 + k], h2[k]);
  }
  float z = b3[0];
#pragma unroll
  for (int k = 0; k < 32; ++k) z = fmaf(fmaxf(h2[k], 0.f), W3[k], z);

  float u = fmaxf(z, 0.f) + log1pf(expf(-fabsf(z)));

  out[O0 + gid] = energy;
  out[O1 + gid] = u;
  out[O2 + gid] = frac;
  out[O3 + gid] = frac * u;
  out[O6 + gid] = merr;
}

// ---------------------------------------------------------------------------
// Per-mode reductions over the 512-image axis: spectra + Pearson correlation.
__global__ __launch_bounds__(64) void corr_kernel(float* __restrict__ out)
{
  int mode = blockIdx.x;     // 0..1023
  int lane = threadIdx.x;    // 0..63

  double su = 0.0, se = 0.0, sen = 0.0, suu = 0.0, see = 0.0, sue = 0.0;
  for (int i = lane; i < NIMG; i += 64) {
    float u  = out[O1 + (size_t)i * 1024 + mode];
    float e  = out[O6 + (size_t)i * 1024 + mode];
    float en = out[O0 + (size_t)i * 1024 + mode];
    su  += (double)u;  se  += (double)e;  sen += (double)en;
    suu += (double)u * (double)u;
    see += (double)e * (double)e;
    sue += (double)u * (double)e;
  }
#pragma unroll
  for (int off = 32; off >= 1; off >>= 1) {
    su  += __shfl_down(su,  off);
    se  += __shfl_down(se,  off);
    sen += __shfl_down(sen, off);
    suu += __shfl_down(suu, off);
    see += __shfl_down(see, off);
    sue += __shfl_down(sue, off);
  }
  if (lane == 0) {
    const double N = (double)NIMG;
    double num = sue - su * se / N;
    double du  = suu - su * su / N;
    double de  = see - se * se / N;
    double den = sqrt(du * de);
    out[O4 + mode] = (float)(su / N);
    out[O5 + mode] = (float)(sen / N);
    out[O7 + mode] = (float)(num / (den + 1e-8));
  }
}

// ---------------------------------------------------------------------------
extern "C" void kernel_launch(void* const* d_in, const int* in_sizes, int n_in,
                              void* d_out, int out_size, void* d_ws, size_t ws_size,
                              hipStream_t stream)
{
  const float* pred = (const float*)d_in[0];
  const float* gt   = (const float*)d_in[2];
  const float* W1   = (const float*)d_in[3];
  const float* b1   = (const float*)d_in[4];
  const float* W2   = (const float*)d_in[5];
  const float* b2   = (const float*)d_in[6];
  const float* W3   = (const float*)d_in[7];
  const float* b3   = (const float*)d_in[8];

  float* out = (float*)d_out;
  float* ws  = (float*)d_ws;
  float* Pm  = ws + PM_OFF;
  float* Gm  = ws + GM_OFF;
  float* tot = ws + TOT_OFF;

  hipLaunchKernelGGL(dft_kernel, dim3(1024), dim3(256), 0, stream,
                     pred, gt, Pm, Gm, tot, out + O0);
  hipLaunchKernelGGL(mlp_kernel, dim3(2048), dim3(256), 0, stream,
                     Pm, Gm, tot, W1, b1, W2, b2, W3, b3, out);
  hipLaunchKernelGGL(corr_kernel, dim3(1024), dim3(64), 0, stream, out);
}

// Round 13
// 124.563 us; speedup vs baseline: 1.2323x; 1.2323x over previous
//
#include <hip/hip_runtime.h>
#include <math.h>

// Problem constants
#define NIMG 512          // B*C = 64*8
#define HH   256          // H
#define MM   32           // M (kept modes per axis)
#define EPSF 1e-8f
#define PAD2 18           // T2 row stride in float2 (144B rows)

// d_out float offsets (outputs concatenated flat in reference return order)
#define O0 0u             // modal_energies        [512][32][32]
#define O1 524288u        // modal_uncertainties   [512][32][32]
#define O2 1048576u       // energy_fractions      [512][32][32]
#define O3 1572864u       // weighted_importance   [512][32][32]
#define O4 2097152u       // uncertainty_spectrum  [32][32]
#define O5 2098176u       // energy_spectrum       [32][32]
#define O6 2099200u       // modal_errors          [512][32][32]
#define O7 2623488u       // calibration_scores    [32][32]

// d_ws float offsets
#define PM_OFF  512                          // pred modes [512][32][32][2]
#define GM_OFF  (512 + NIMG*MM*MM*2)         // gt modes
#define TOT_OFF (512 + 2*NIMG*MM*MM*2)       // per-image HALF energies [512][2]

// ---------------------------------------------------------------------------
// Truncated 2D DFT, k1-PARITY-SPLIT: TWO blocks per (image, tensor);
// block half=0 computes even k1 (via s[n1]=x[n1]+x[n1+128], a 128-pt DFT),
// half=1 computes odd k1 (via d[n1]=x[n1]-x[n1+128] with W256^n1 pre-twist).
// Per-thread state: 16 complex accs = 32 floats (vs 64 in r3-r12) -> fits the
// allocator's natural 128-VGPR budget at 4 blocks/CU; no AGPR shuttle.
// Stage 1 (DIT-8 over n1' = a + 16b, a<16): 8-pt kernel over b (even:
//   standard real 8-pt DFT; odd: odd-index kernel, compile-time constants),
//   then X[8m+r] += W16^{am} * Y_r(a); twiddles from 2KB LDS table
//   (wave-uniform reads); input 2-buffer ping-pong prefetch (16 regs each).
// Stage 2: single pass (16 k1 rows in T2[256][18]); thread -> (k1l=l>>2,
//   k2 = 4*(l&3)+wave, +16); radix-4 fold over n2, residue wave-uniform;
//   rotator recurrence. Global k1 = 2*k1l + half.
// XCD-chunked block swizzle pairs (img,half=0/1) on one XCD -> 2nd read of
// the image hits that XCD's L2 (image = 256KB << 4MB).
__global__ __launch_bounds__(256) void dft_kernel(
    const float* __restrict__ pred, const float* __restrict__ gt,
    float* __restrict__ Pm, float* __restrict__ Gm,
    float* __restrict__ totp, float* __restrict__ out_energy)
{
  __shared__ __align__(16) float2 T2[256 * PAD2];   // 36864 B
  __shared__ float2 tws[256];                       // 2 KB twiddle table
  __shared__ float red[4];

  const int t    = threadIdx.x;
  const int w    = t >> 6;           // wave 0..3
  const int l    = t & 63;
  // XCD-chunked swizzle (2048 = 8 XCD x 256): physical p -> logical so that
  // consecutive logical ids (the img half-pair) land on the same XCD.
  const int p    = blockIdx.x;
  const int lbid = (p & 7) * 256 + (p >> 3);
  const int half = lbid & 1;
  const int img  = (lbid >> 1) & (NIMG - 1);
  const int isGt = lbid >> 10;
  const float* __restrict__ x =
      (isGt ? gt : pred) + (size_t)img * (HH * HH);

  // twiddle table: tws[i] = (cos, sin)(2*pi*i/256)
  {
    float sn, cs;
    __sincosf((float)(2.0 * M_PI / 256.0) * (float)t, &sn, &cs);
    tws[t] = make_float2(cs, sn);
  }
  __syncthreads();

  // ---- stage 1 ----
  float accR[16], accI[16];
#pragma unroll
  for (int k = 0; k < 16; ++k) { accR[k] = 0.f; accI[k] = 0.f; }

  // ACC2: X[r] += Y ; X[8+r] += (tm.x, -tm.y) (x) Y   (tm = W16^a)
#define ACC2(r, Yr, Yi)                                                   \
    accR[(r)] += (Yr);  accI[(r)] += (Yi);                                \
    accR[8+(r)] = fmaf(tm.x,(Yr), fmaf( tm.y,(Yi), accR[8+(r)]));         \
    accI[8+(r)] = fmaf(tm.x,(Yi), fmaf(-(tm.y),(Yr), accI[8+(r)]));

#define CPLX_E(r, aa, Zr, Zi)                                             \
    { float2 tt = tws[(2*(r)*(aa)) & 255];                                \
      float Yr = fmaf(tt.x,(Zr),  tt.y*(Zi));                             \
      float Yi = fmaf(tt.x,(Zi), -(tt.y*(Zr)));                           \
      ACC2(r, Yr, Yi) }

#define CPLX_O(r, j, aa, Dr, Di)                                          \
    { float2 tt = tws[((j)*(aa)) & 255];                                  \
      float Yr = fmaf(tt.x,(Dr),  tt.y*(Di));                             \
      float Yi = fmaf(tt.x,(Di), -(tt.y*(Dr)));                           \
      ACC2(r, Yr, Yi) }

#define LOADV(V, aa)                                                      \
    V[0]  = x[((aa)      )*256 + t]; V[1]  = x[((aa) +  16)*256 + t];     \
    V[2]  = x[((aa) +  32)*256 + t]; V[3]  = x[((aa) +  48)*256 + t];     \
    V[4]  = x[((aa) +  64)*256 + t]; V[5]  = x[((aa) +  80)*256 + t];     \
    V[6]  = x[((aa) +  96)*256 + t]; V[7]  = x[((aa) + 112)*256 + t];     \
    V[8]  = x[((aa) + 128)*256 + t]; V[9]  = x[((aa) + 144)*256 + t];     \
    V[10] = x[((aa) + 160)*256 + t]; V[11] = x[((aa) + 176)*256 + t];     \
    V[12] = x[((aa) + 192)*256 + t]; V[13] = x[((aa) + 208)*256 + t];     \
    V[14] = x[((aa) + 224)*256 + t]; V[15] = x[((aa) + 240)*256 + t];

  // EVEN half: s_b = V[b]+V[b+8]; standard real 8-pt DFT; Y_r = W128^{ar} Z_r
#define BODY_E(V, aa)                                                     \
  {                                                                       \
    float s0=V[0]+V[8],  s1=V[1]+V[9],  s2=V[2]+V[10], s3=V[3]+V[11];     \
    float s4=V[4]+V[12], s5=V[5]+V[13], s6=V[6]+V[14], s7=V[7]+V[15];     \
    float w0=s0+s4, w1=s1+s5, w2=s2+s6, w3=s3+s7;                         \
    float e0=s0-s4, e1=s1-s5, e2=s2-s6, e3=s3-s7;                         \
    float A0=w0+w2, A1=w0-w2, A2=w1+w3, A3=w1-w3;                         \
    float Z0=A0+A2, Z4=A0-A2;                                             \
    float Z2r=A1, Z2i=-A3;                                                \
    float pp=0.70710678f*(e1-e3), qq2=0.70710678f*(e1+e3);                \
    float Z1r=e0+pp, Z1i=-(e2+qq2);                                       \
    float Z3r=e0-pp, Z3i=e2-qq2;                                          \
    float2 tm = tws[(16*(aa)) & 255];                                     \
    accR[0] += Z0;                                                        \
    accR[8] = fmaf(tm.x,Z0,accR[8]); accI[8] = fmaf(-tm.y,Z0,accI[8]);    \
    { float2 tt = tws[(8*(aa)) & 255];                                    \
      float Yr = tt.x*Z4, Yi = -(tt.y*Z4);                                \
      ACC2(4, Yr, Yi) }                                                   \
    CPLX_E(1,(aa),Z1r, Z1i) CPLX_E(2,(aa),Z2r, Z2i) CPLX_E(3,(aa),Z3r, Z3i) \
    CPLX_E(5,(aa),Z3r,-Z3i) CPLX_E(6,(aa),Z2r,-Z2i) CPLX_E(7,(aa),Z1r,-Z1i) \
  }

  // ODD half: d_b = V[b]-V[b+8]; odd-index 8-pt kernel (freq (2r+1)/16);
  // D_{7-r} = conj(D_r); Y_r = W256^{a(2r+1)} D_r
#define BODY_O(V, aa)                                                     \
  {                                                                       \
    float d0=V[0]-V[8],  d1=V[1]-V[9],  d2=V[2]-V[10], d3=V[3]-V[11];     \
    float d4=V[4]-V[12], d5=V[5]-V[13], d6=V[6]-V[14], d7=V[7]-V[15];     \
    float p1=d1-d7, p2=d2-d6, p3=d3-d5;                                   \
    float q1=d1+d7, q2=d2+d6, q3=d3+d5;                                   \
    float R0=d0+fmaf(0.92387953f,p1,fmaf( 0.70710678f,p2, 0.38268343f*p3)); \
    float I0=-d4-fmaf(0.38268343f,q1,fmaf( 0.70710678f,q2, 0.92387953f*q3)); \
    float R1=d0+fmaf(0.38268343f,p1,fmaf(-0.70710678f,p2,-0.92387953f*p3)); \
    float I1= d4-fmaf(0.92387953f,q1,fmaf( 0.70710678f,q2,-0.38268343f*q3)); \
    float R2=d0+fmaf(-0.38268343f,p1,fmaf(-0.70710678f,p2, 0.92387953f*p3)); \
    float I2=-d4-fmaf( 0.92387953f,q1,fmaf(-0.70710678f,q2,-0.38268343f*q3)); \
    float R3=d0+fmaf(-0.92387953f,p1,fmaf( 0.70710678f,p2,-0.38268343f*p3)); \
    float I3= d4-fmaf( 0.38268343f,q1,fmaf(-0.70710678f,q2, 0.92387953f*q3)); \
    float2 tm = tws[(16*(aa)) & 255];                                     \
    CPLX_O(0, 1,(aa),R0, I0) CPLX_O(1, 3,(aa),R1, I1)                     \
    CPLX_O(2, 5,(aa),R2, I2) CPLX_O(3, 7,(aa),R3, I3)                     \
    CPLX_O(4, 9,(aa),R3,-I3) CPLX_O(5,11,(aa),R2,-I2)                     \
    CPLX_O(6,13,(aa),R1,-I1) CPLX_O(7,15,(aa),R0,-I0)                     \
  }

  {
    float vA[16], vB[16];
    if (half == 0) {
      LOADV(vA, 0)
      LOADV(vB, 1)
#pragma unroll 1
      for (int a = 0; a < 16; a += 2) {
        BODY_E(vA, a)
        if (a < 14) { LOADV(vA, a + 2) }
        BODY_E(vB, a + 1)
        if (a < 14) { LOADV(vB, a + 3) }
      }
    } else {
      LOADV(vA, 0)
      LOADV(vB, 1)
#pragma unroll 1
      for (int a = 0; a < 16; a += 2) {
        BODY_O(vA, a)
        if (a < 14) { LOADV(vA, a + 2) }
        BODY_O(vB, a + 1)
        if (a < 14) { LOADV(vB, a + 3) }
      }
    }
  }
#undef BODY_E
#undef BODY_O
#undef LOADV
#undef CPLX_E
#undef CPLX_O
#undef ACC2

  // ---- stage 2: single pass, radix-4 fold over n2 ----
  float* __restrict__ Mo = (isGt ? Gm : Pm) + (size_t)img * (MM * MM * 2);
  const int wv  = w;             // residue k2 % 4 (wave-uniform)
  const int k1l = l >> 2;        // local k1 row 0..15
  const int qq  = l & 3;
  const int k2A = 4 * qq + wv;
  const int k2B = k2A + 16;
  float sA, cA, sB, cB;
  __sincosf((float)(-2.0 * M_PI / 256.0) * (float)k2A, &sA, &cA);
  __sincosf((float)(-2.0 * M_PI / 256.0) * (float)k2B, &sB, &cB);
  const float se = (wv & 1) ? -1.f : 1.f;     // fold sign for T_c/T_3
  const float cc = (wv < 2) ? 1.f : -1.f;     // second-term sign
  const bool  ev = (wv & 1) == 0;

  // flush 16 accs -> T2[t][0..15]
  {
    float4* rowp = (float4*)&T2[t * PAD2];
    rowp[0] = make_float4(accR[ 0],accI[ 0],accR[ 1],accI[ 1]);
    rowp[1] = make_float4(accR[ 2],accI[ 2],accR[ 3],accI[ 3]);
    rowp[2] = make_float4(accR[ 4],accI[ 4],accR[ 5],accI[ 5]);
    rowp[3] = make_float4(accR[ 6],accI[ 6],accR[ 7],accI[ 7]);
    rowp[4] = make_float4(accR[ 8],accI[ 8],accR[ 9],accI[ 9]);
    rowp[5] = make_float4(accR[10],accI[10],accR[11],accI[11]);
    rowp[6] = make_float4(accR[12],accI[12],accR[13],accI[13]);
    rowp[7] = make_float4(accR[14],accI[14],accR[15],accI[15]);
  }
  __syncthreads();

  float eacc = 0.f;
  {
    float wAr = 1.f, wAi = 0.f, wBr = 1.f, wBi = 0.f;
    float XAr = 0.f, XAi = 0.f, XBr = 0.f, XBi = 0.f;
#pragma unroll 4
    for (int n2 = 0; n2 < 64; ++n2) {
      float2 T0 = T2[(n2      ) * PAD2 + k1l];
      float2 T1 = T2[(n2 +  64) * PAD2 + k1l];
      float2 Tc = T2[(n2 + 128) * PAD2 + k1l];
      float2 T3 = T2[(n2 + 192) * PAD2 + k1l];
      float sr = fmaf(se, Tc.x, T0.x), si = fmaf(se, Tc.y, T0.y);
      float tr = fmaf(se, T3.x, T1.x), ti = fmaf(se, T3.y, T1.y);
      float ur = ev ? tr : ti;
      float ui = ev ? ti : -tr;
      float yr = fmaf(cc, ur, sr), yi = fmaf(cc, ui, si);
      XAr = fmaf(wAr, yr, fmaf(-wAi, yi, XAr));
      XAi = fmaf(wAr, yi, fmaf( wAi, yr, XAi));
      XBr = fmaf(wBr, yr, fmaf(-wBi, yi, XBr));
      XBi = fmaf(wBr, yi, fmaf( wBi, yr, XBi));
      float nAr = fmaf(wAr, cA, -(wAi * sA));
      float nAi = fmaf(wAr, sA,  (wAi * cA));
      float nBr = fmaf(wBr, cB, -(wBi * sB));
      float nBi = fmaf(wBr, sB,  (wBi * cB));
      wAr = nAr; wAi = nAi; wBr = nBr; wBi = nBi;
    }
    const int k1g = 2 * k1l + half;          // parity-split global k1
    const int mA  = k1g * MM + k2A;
    const int mB  = k1g * MM + k2B;
    ((float2*)Mo)[mA] = make_float2(XAr, XAi);
    ((float2*)Mo)[mB] = make_float2(XBr, XBi);
    if (!isGt) {
      float eA = fmaf(XAr, XAr, XAi * XAi);
      float eB = fmaf(XBr, XBr, XBi * XBi);
      out_energy[(size_t)img * (MM * MM) + mA] = eA;
      out_energy[(size_t)img * (MM * MM) + mB] = eB;
      eacc += eA + eB;
    }
  }

  if (!isGt) {   // block-uniform branch: per-half partial energy
#pragma unroll
    for (int off = 32; off >= 1; off >>= 1) eacc += __shfl_down(eacc, off);
    if (l == 0) red[w] = eacc;
    __syncthreads();
    if (t == 0) totp[2 * img + half] = (red[0] + red[1]) + (red[2] + red[3]);
  }
}

// ---------------------------------------------------------------------------
// Per-mode MLP + elementwise outputs. One thread per (img, mode).
__global__ __launch_bounds__(256) void mlp_kernel(
    const float* __restrict__ Pm, const float* __restrict__ Gm,
    const float* __restrict__ totp,
    const float* __restrict__ W1, const float* __restrict__ b1,
    const float* __restrict__ W2, const float* __restrict__ b2,
    const float* __restrict__ W3, const float* __restrict__ b3,
    float* __restrict__ out)
{
  int gid = blockIdx.x * 256 + threadIdx.x;   // 0 .. 524287
  int img = gid >> 10;

  float2 pm = *(const float2*)&Pm[2 * (size_t)gid];
  float2 gm = *(const float2*)&Gm[2 * (size_t)gid];

  float er = pm.x - gm.x, ei = pm.y - gm.y;
  float merr   = fmaf(er, er, ei * ei);
  float energy = fmaf(pm.x, pm.x, pm.y * pm.y);
  float tot    = totp[2 * img] + totp[2 * img + 1];
  float frac   = energy / (tot + EPSF);

  float h1[64];
#pragma unroll
  for (int j = 0; j < 64; ++j)
    h1[j] = fmaxf(fmaf(pm.x, W1[j], fmaf(pm.y, W1[64 + j], b1[j])), 0.f);

  float h2[32];
#pragma unroll
  for (int k = 0; k < 32; ++k) h2[k] = b2[k];
#pragma unroll
  for (int j = 0; j < 64; ++j) {
#pragma unroll
    for (int k = 0; k < 32; ++k)
      h2[k] = fmaf(h1[j], W2[j * 32 + k], h2[k]);
  }
  float z = b3[0];
#pragma unroll
  for (int k = 0; k < 32; ++k) z = fmaf(fmaxf(h2[k], 0.f), W3[k], z);

  float u = fmaxf(z, 0.f) + log1pf(expf(-fabsf(z)));

  out[O0 + gid] = energy;
  out[O1 + gid] = u;
  out[O2 + gid] = frac;
  out[O3 + gid] = frac * u;
  out[O6 + gid] = merr;
}

// ---------------------------------------------------------------------------
// Per-mode reductions over the 512-image axis: spectra + Pearson correlation.
__global__ __launch_bounds__(64) void corr_kernel(float* __restrict__ out)
{
  int mode = blockIdx.x;     // 0..1023
  int lane = threadIdx.x;    // 0..63

  double su = 0.0, se = 0.0, sen = 0.0, suu = 0.0, see = 0.0, sue = 0.0;
  for (int i = lane; i < NIMG; i += 64) {
    float u  = out[O1 + (size_t)i * 1024 + mode];
    float e  = out[O6 + (size_t)i * 1024 + mode];
    float en = out[O0 + (size_t)i * 1024 + mode];
    su  += (double)u;  se  += (double)e;  sen += (double)en;
    suu += (double)u * (double)u;
    see += (double)e * (double)e;
    sue += (double)u * (double)e;
  }
#pragma unroll
  for (int off = 32; off >= 1; off >>= 1) {
    su  += __shfl_down(su,  off);
    se  += __shfl_down(se,  off);
    sen += __shfl_down(sen, off);
    suu += __shfl_down(suu, off);
    see += __shfl_down(see, off);
    sue += __shfl_down(sue, off);
  }
  if (lane == 0) {
    const double N = (double)NIMG;
    double num = sue - su * se / N;
    double du  = suu - su * su / N;
    double de  = see - se * se / N;
    double den = sqrt(du * de);
    out[O4 + mode] = (float)(su / N);
    out[O5 + mode] = (float)(sen / N);
    out[O7 + mode] = (float)(num / (den + 1e-8));
  }
}

// ---------------------------------------------------------------------------
extern "C" void kernel_launch(void* const* d_in, const int* in_sizes, int n_in,
                              void* d_out, int out_size, void* d_ws, size_t ws_size,
                              hipStream_t stream)
{
  const float* pred = (const float*)d_in[0];
  const float* gt   = (const float*)d_in[2];
  const float* W1   = (const float*)d_in[3];
  const float* b1   = (const float*)d_in[4];
  const float* W2   = (const float*)d_in[5];
  const float* b2   = (const float*)d_in[6];
  const float* W3   = (const float*)d_in[7];
  const float* b3   = (const float*)d_in[8];

  float* out  = (float*)d_out;
  float* ws   = (float*)d_ws;
  float* Pm   = ws + PM_OFF;
  float* Gm   = ws + GM_OFF;
  float* totp = ws + TOT_OFF;

  hipLaunchKernelGGL(dft_kernel, dim3(2048), dim3(256), 0, stream,
                     pred, gt, Pm, Gm, totp, out + O0);
  hipLaunchKernelGGL(mlp_kernel, dim3(2048), dim3(256), 0, stream,
                     Pm, Gm, totp, W1, b1, W2, b2, W3, b3, out);
  hipLaunchKernelGGL(corr_kernel, dim3(1024), dim3(64), 0, stream, out);
}